// Round 4
// baseline (243.780 us; speedup 1.0000x reference)
//
#include <hip/hip_runtime.h>

#define D 128
#define BN_EPS 1e-5f
#define NB_AGG 2048

__device__ __forceinline__ unsigned bf16rne(float f) {
    unsigned u = __float_as_uint(f);
    return (u + 0x7fffu + ((u >> 16) & 1u)) >> 16;
}
__device__ __forceinline__ float bflo(unsigned p) { return __uint_as_float(p << 16); }
__device__ __forceinline__ float bfhi(unsigned p) { return __uint_as_float(p & 0xffff0000u); }

// ---------------- degree count ----------------
__global__ void count_deg(const int* __restrict__ col, int* __restrict__ counts, int E) {
    int e = blockIdx.x * blockDim.x + threadIdx.x;
    if (e < E) atomicAdd(&counts[col[e]], 1);
}

// ---------------- dis + per-block sums (fused) ----------------
__global__ __launch_bounds__(256) void dis_scan_p1(const int* __restrict__ counts,
                                                   float* __restrict__ dis,
                                                   int* __restrict__ blocksums, int n) {
    __shared__ int lds[256];
    int tid = threadIdx.x;
    int i = blockIdx.x * 256 + tid;
    int c = (i < n) ? counts[i] : 0;
    if (i < n) dis[i] = rsqrtf((float)c + 1.0f);
    lds[tid] = c;
    __syncthreads();
    for (int d = 128; d > 0; d >>= 1) {
        if (tid < d) lds[tid] += lds[tid + d];
        __syncthreads();
    }
    if (tid == 0) blocksums[blockIdx.x] = lds[0];
}

// ---------------- fused: scan block sums in-block + local scan + offsets ----------------
__global__ __launch_bounds__(256) void scan_p3(const int* __restrict__ counts,
                                               const int* __restrict__ blocksums,
                                               int* __restrict__ offsets,
                                               int* __restrict__ cursor, int n, int nb) {
    __shared__ int bs[256];
    __shared__ int lds[256];
    int tid = threadIdx.x;
    // scan the (<=256) per-block sums locally
    bs[tid] = (tid < nb) ? blocksums[tid] : 0;
    __syncthreads();
    for (int d = 1; d < 256; d <<= 1) {
        int t = (tid >= d) ? bs[tid - d] : 0;
        __syncthreads();
        bs[tid] += t;
        __syncthreads();
    }
    int blockoff = (blockIdx.x == 0) ? 0 : bs[blockIdx.x - 1];
    // local scan of this block's counts
    int i = blockIdx.x * 256 + tid;
    int v = (i < n) ? counts[i] : 0;
    lds[tid] = v;
    __syncthreads();
    for (int d = 1; d < 256; d <<= 1) {
        int t = (tid >= d) ? lds[tid - d] : 0;
        __syncthreads();
        lds[tid] += t;
        __syncthreads();
    }
    if (i < n) {
        int off = blockoff + lds[tid] - v;
        offsets[i] = off;
        cursor[i] = off;
        if (i == n - 1) offsets[n] = off + v;
    }
}

// ---------------- CSR fill: (src, dis[src]) pairs sorted by dest ----------------
__global__ void fill_csr(const int* __restrict__ row, const int* __restrict__ col,
                         const float* __restrict__ dis, int* __restrict__ cursor,
                         int2* __restrict__ epair, int E) {
    int e = blockIdx.x * blockDim.x + threadIdx.x;
    if (e < E) {
        int c = col[e];
        int r = row[e];
        int p = atomicAdd(&cursor[c], 1);
        epair[p] = make_int2(r, __float_as_int(dis[r]));
    }
}

// ---------------- h = x @ W (fp32 compute, bf16 store) ----------------
__global__ __launch_bounds__(256) void gemm_xw(const float* __restrict__ x,
                                               const float* __restrict__ W,
                                               unsigned* __restrict__ hb, int n) {
    __shared__ float xs[32][68];
    __shared__ float ws[32][128];
    int tid = threadIdx.x;
    int tx = tid & 31;
    int ty = tid >> 5;
    int row0 = blockIdx.x * 64;
    float acc[8][4] = {};

    for (int k0 = 0; k0 < 128; k0 += 32) {
        #pragma unroll
        for (int i = 0; i < 2; i++) {
            int li = tid + i * 256;
            int r = li >> 3;
            int kq = li & 7;
            int grow = row0 + r;
            if (grow >= n) grow = n - 1;
            float4 v = *(const float4*)&x[(size_t)grow * D + k0 + kq * 4];
            xs[kq * 4 + 0][r] = v.x;
            xs[kq * 4 + 1][r] = v.y;
            xs[kq * 4 + 2][r] = v.z;
            xs[kq * 4 + 3][r] = v.w;
        }
        #pragma unroll
        for (int i = 0; i < 4; i++) {
            int li = tid + i * 256;
            int c4 = li & 31;
            int k = li >> 5;
            *(float4*)&ws[k][c4 * 4] = *(const float4*)&W[(size_t)(k0 + k) * D + c4 * 4];
        }
        __syncthreads();
        #pragma unroll
        for (int k = 0; k < 32; k++) {
            float4 wv = *(const float4*)&ws[k][tx * 4];
            float xr[8];
            *(float4*)&xr[0] = *(const float4*)&xs[k][ty * 8];
            *(float4*)&xr[4] = *(const float4*)&xs[k][ty * 8 + 4];
            #pragma unroll
            for (int r = 0; r < 8; r++) {
                acc[r][0] += xr[r] * wv.x;
                acc[r][1] += xr[r] * wv.y;
                acc[r][2] += xr[r] * wv.z;
                acc[r][3] += xr[r] * wv.w;
            }
        }
        __syncthreads();
    }
    #pragma unroll
    for (int r = 0; r < 8; r++) {
        int gr = row0 + ty * 8 + r;
        if (gr < n) {
            uint2 pk;
            pk.x = bf16rne(acc[r][0]) | (bf16rne(acc[r][1]) << 16);
            pk.y = bf16rne(acc[r][2]) | (bf16rne(acc[r][3]) << 16);
            *(uint2*)&hb[(size_t)gr * 64 + tx * 2] = pk;
        }
    }
}

// ---------------- aggregation: half-wave per node (2 nodes/wave), bf16 gather, fused BN stats ----------------
__global__ __launch_bounds__(256) void aggregate(const uint2* __restrict__ hbq,
                                                 const float* __restrict__ dis,
                                                 const int* __restrict__ offsets,
                                                 const int2* __restrict__ epair,
                                                 const float* __restrict__ bias,
                                                 float* __restrict__ out,
                                                 float* __restrict__ gsum,
                                                 float* __restrict__ gsumsq, int n) {
    int tid = threadIdx.x;
    int wave = tid >> 6;
    int lane = tid & 63;
    int half = lane >> 5;
    int sub = lane & 31;
    float4 bv = *(const float4*)&bias[sub * 4];
    float p1x = 0.f, p1y = 0.f, p1z = 0.f, p1w = 0.f;
    float p2x = 0.f, p2y = 0.f, p2z = 0.f, p2w = 0.f;

    for (int node = blockIdx.x * 8 + wave * 2 + half; node < n; node += gridDim.x * 8) {
        float dc = dis[node];
        int s0 = offsets[node], s1 = offsets[node + 1];
        int cnt = s1 - s0;
        uint2 hq = hbq[(size_t)node * 32 + sub];
        float ax = dc * bflo(hq.x), ay = dc * bfhi(hq.x);
        float az = dc * bflo(hq.y), aw = dc * bfhi(hq.y);
        // lane-parallel preload of up to 32 (src, dis) pairs per half-wave
        int2 ep = (sub < cnt) ? epair[s0 + sub] : make_int2(0, 0);
        int cap = cnt < 32 ? cnt : 32;
        int e = 0;
        for (; e + 4 <= cap; e += 4) {
            int sA = __shfl(ep.x, e, 32), sB = __shfl(ep.x, e + 1, 32);
            int sC = __shfl(ep.x, e + 2, 32), sD = __shfl(ep.x, e + 3, 32);
            float dA = __int_as_float(__shfl(ep.y, e, 32));
            float dB = __int_as_float(__shfl(ep.y, e + 1, 32));
            float dC = __int_as_float(__shfl(ep.y, e + 2, 32));
            float dD = __int_as_float(__shfl(ep.y, e + 3, 32));
            uint2 hA = hbq[(size_t)sA * 32 + sub];
            uint2 hB = hbq[(size_t)sB * 32 + sub];
            uint2 hC = hbq[(size_t)sC * 32 + sub];
            uint2 hD = hbq[(size_t)sD * 32 + sub];
            ax += dA * bflo(hA.x); ay += dA * bfhi(hA.x); az += dA * bflo(hA.y); aw += dA * bfhi(hA.y);
            ax += dB * bflo(hB.x); ay += dB * bfhi(hB.x); az += dB * bflo(hB.y); aw += dB * bfhi(hB.y);
            ax += dC * bflo(hC.x); ay += dC * bfhi(hC.x); az += dC * bflo(hC.y); aw += dC * bfhi(hC.y);
            ax += dD * bflo(hD.x); ay += dD * bfhi(hD.x); az += dD * bflo(hD.y); aw += dD * bfhi(hD.y);
        }
        for (; e < cap; e++) {
            int s = __shfl(ep.x, e, 32);
            float dv = __int_as_float(__shfl(ep.y, e, 32));
            uint2 hE = hbq[(size_t)s * 32 + sub];
            ax += dv * bflo(hE.x); ay += dv * bfhi(hE.x); az += dv * bflo(hE.y); aw += dv * bfhi(hE.y);
        }
        for (e = 32; e < cnt; e++) {  // rare deg>32 tail (uniform broadcast load)
            int2 q = epair[s0 + e];
            float dv = __int_as_float(q.y);
            uint2 hE = hbq[(size_t)q.x * 32 + sub];
            ax += dv * bflo(hE.x); ay += dv * bfhi(hE.x); az += dv * bflo(hE.y); aw += dv * bfhi(hE.y);
        }
        float ox = dc * ax + bv.x;
        float oy = dc * ay + bv.y;
        float oz = dc * az + bv.z;
        float ow = dc * aw + bv.w;
        *(float4*)&out[(size_t)node * D + sub * 4] = make_float4(ox, oy, oz, ow);
        p1x += ox; p1y += oy; p1z += oz; p1w += ow;
        p2x += ox * ox; p2y += oy * oy; p2z += oz * oz; p2w += ow * ow;
    }

    // combine halves (same column set), then cross-wave LDS reduce, then 256 atomics
    p1x += __shfl_xor(p1x, 32); p1y += __shfl_xor(p1y, 32);
    p1z += __shfl_xor(p1z, 32); p1w += __shfl_xor(p1w, 32);
    p2x += __shfl_xor(p2x, 32); p2y += __shfl_xor(p2y, 32);
    p2z += __shfl_xor(p2z, 32); p2w += __shfl_xor(p2w, 32);
    __shared__ float l1[4][128], l2[4][128];
    if (half == 0) {
        *(float4*)&l1[wave][sub * 4] = make_float4(p1x, p1y, p1z, p1w);
        *(float4*)&l2[wave][sub * 4] = make_float4(p2x, p2y, p2z, p2w);
    }
    __syncthreads();
    if (tid < 128) {
        float a = l1[0][tid] + l1[1][tid] + l1[2][tid] + l1[3][tid];
        float b = l2[0][tid] + l2[1][tid] + l2[2][tid] + l2[3][tid];
        atomicAdd(&gsum[tid], a);
        atomicAdd(&gsumsq[tid], b);
    }
}

// ---------------- BN finalize + ReLU (in place, float4) ----------------
__global__ __launch_bounds__(256) void bn_finalize(float4* __restrict__ out4,
                                                   const float* __restrict__ gsum,
                                                   const float* __restrict__ gsumsq,
                                                   const float* __restrict__ gamma,
                                                   const float* __restrict__ beta,
                                                   int total4, float invN) {
    int i0 = blockIdx.x * 256 + threadIdx.x;
    int c = (i0 * 4) & 127;  // stride (grid*1024 floats) is a multiple of 128 -> col quad constant
    float4 g4 = *(const float4*)&gsum[c];
    float4 q4 = *(const float4*)&gsumsq[c];
    float4 gm = *(const float4*)&gamma[c];
    float4 bt = *(const float4*)&beta[c];
    float m0 = g4.x * invN, m1 = g4.y * invN, m2 = g4.z * invN, m3 = g4.w * invN;
    float sc0 = rsqrtf(q4.x * invN - m0 * m0 + BN_EPS) * gm.x;
    float sc1 = rsqrtf(q4.y * invN - m1 * m1 + BN_EPS) * gm.y;
    float sc2 = rsqrtf(q4.z * invN - m2 * m2 + BN_EPS) * gm.z;
    float sc3 = rsqrtf(q4.w * invN - m3 * m3 + BN_EPS) * gm.w;
    float sh0 = bt.x - m0 * sc0, sh1 = bt.y - m1 * sc1;
    float sh2 = bt.z - m2 * sc2, sh3 = bt.w - m3 * sc3;
    for (int i = i0; i < total4; i += gridDim.x * 256) {
        float4 v = out4[i];
        v.x = fmaxf(fmaf(v.x, sc0, sh0), 0.f);
        v.y = fmaxf(fmaf(v.y, sc1, sh1), 0.f);
        v.z = fmaxf(fmaf(v.z, sc2, sh2), 0.f);
        v.w = fmaxf(fmaf(v.w, sc3, sh3), 0.f);
        out4[i] = v;
    }
}

extern "C" void kernel_launch(void* const* d_in, const int* in_sizes, int n_in,
                              void* d_out, int out_size, void* d_ws, size_t ws_size,
                              hipStream_t stream) {
    const float* x     = (const float*)d_in[0];
    const int*   pos   = (const int*)d_in[1];
    const float* W     = (const float*)d_in[3];
    const float* bias  = (const float*)d_in[4];
    const float* gamma = (const float*)d_in[5];
    const float* beta  = (const float*)d_in[6];
    float* out = (float*)d_out;

    int N  = in_sizes[0] / D;
    int EP = in_sizes[1] / 2;
    const int* prow = pos;
    const int* pcol = pos + EP;
    int nb = (N + 255) / 256;  // must be <= 256

    auto align = [](size_t v) { return (v + 255) & ~(size_t)255; };
    char* p = (char*)d_ws;
    int*      counts    = (int*)p;      p += align((size_t)N * 4);
    float*    gsum      = (float*)p;    p += align((size_t)D * 4);
    float*    gsumsq    = (float*)p;    p += align((size_t)D * 4);
    size_t zbytes = (size_t)(p - (char*)d_ws);
    float*    dis       = (float*)p;    p += align((size_t)N * 4);
    int*      offs      = (int*)p;      p += align(((size_t)N + 1) * 4);
    int*      cursor    = (int*)p;      p += align((size_t)N * 4);
    int*      blocksums = (int*)p;      p += align((size_t)256 * 4);
    int2*     epair     = (int2*)p;     p += align((size_t)EP * 8);
    unsigned* hb        = (unsigned*)p; p += align((size_t)N * 64 * 4);

    hipMemsetAsync(d_ws, 0, zbytes, stream);
    count_deg<<<(EP + 255) / 256, 256, 0, stream>>>(pcol, counts, EP);
    dis_scan_p1<<<nb, 256, 0, stream>>>(counts, dis, blocksums, N);
    scan_p3<<<nb, 256, 0, stream>>>(counts, blocksums, offs, cursor, N, nb);
    fill_csr<<<(EP + 255) / 256, 256, 0, stream>>>(prow, pcol, dis, cursor, epair, EP);
    gemm_xw<<<(N + 63) / 64, 256, 0, stream>>>(x, W, hb, N);
    aggregate<<<NB_AGG, 256, 0, stream>>>((const uint2*)hb, dis, offs, epair, bias, out,
                                          gsum, gsumsq, N);
    bn_finalize<<<1600, 256, 0, stream>>>((float4*)out, gsum, gsumsq, gamma, beta,
                                          N * D / 4, 1.0f / (float)N);
}

// Round 5
// 243.090 us; speedup vs baseline: 1.0028x; 1.0028x over previous
//
#include <hip/hip_runtime.h>

#define D 128
#define BN_EPS 1e-5f
#define NB_AGG 2048

__device__ __forceinline__ unsigned bf16rne(float f) {
    unsigned u = __float_as_uint(f);
    return (u + 0x7fffu + ((u >> 16) & 1u)) >> 16;
}
__device__ __forceinline__ float bflo(unsigned p) { return __uint_as_float(p << 16); }
__device__ __forceinline__ float bfhi(unsigned p) { return __uint_as_float(p & 0xffff0000u); }

// ---------------- degree count ----------------
__global__ void count_deg(const int* __restrict__ col, int* __restrict__ counts, int E) {
    int e = blockIdx.x * blockDim.x + threadIdx.x;
    if (e < E) atomicAdd(&counts[col[e]], 1);
}

// ---------------- dis + per-block sums (fused) ----------------
__global__ __launch_bounds__(256) void dis_scan_p1(const int* __restrict__ counts,
                                                   float* __restrict__ dis,
                                                   int* __restrict__ blocksums, int n) {
    __shared__ int lds[256];
    int tid = threadIdx.x;
    int i = blockIdx.x * 256 + tid;
    int c = (i < n) ? counts[i] : 0;
    if (i < n) dis[i] = rsqrtf((float)c + 1.0f);
    lds[tid] = c;
    __syncthreads();
    for (int d = 128; d > 0; d >>= 1) {
        if (tid < d) lds[tid] += lds[tid + d];
        __syncthreads();
    }
    if (tid == 0) blocksums[blockIdx.x] = lds[0];
}

// ---------------- fused: scan block sums in-block + local scan + offsets ----------------
__global__ __launch_bounds__(256) void scan_p3(const int* __restrict__ counts,
                                               const int* __restrict__ blocksums,
                                               int* __restrict__ offsets,
                                               int* __restrict__ cursor, int n, int nb) {
    __shared__ int bs[256];
    __shared__ int lds[256];
    int tid = threadIdx.x;
    bs[tid] = (tid < nb) ? blocksums[tid] : 0;
    __syncthreads();
    for (int d = 1; d < 256; d <<= 1) {
        int t = (tid >= d) ? bs[tid - d] : 0;
        __syncthreads();
        bs[tid] += t;
        __syncthreads();
    }
    int blockoff = (blockIdx.x == 0) ? 0 : bs[blockIdx.x - 1];
    int i = blockIdx.x * 256 + tid;
    int v = (i < n) ? counts[i] : 0;
    lds[tid] = v;
    __syncthreads();
    for (int d = 1; d < 256; d <<= 1) {
        int t = (tid >= d) ? lds[tid - d] : 0;
        __syncthreads();
        lds[tid] += t;
        __syncthreads();
    }
    if (i < n) {
        int off = blockoff + lds[tid] - v;
        offsets[i] = off;
        cursor[i] = off;
        if (i == n - 1) offsets[n] = off + v;
    }
}

// ---------------- CSR fill: (src, dis[src]) pairs sorted by dest ----------------
__global__ void fill_csr(const int* __restrict__ row, const int* __restrict__ col,
                         const float* __restrict__ dis, int* __restrict__ cursor,
                         int2* __restrict__ epair, int E) {
    int e = blockIdx.x * blockDim.x + threadIdx.x;
    if (e < E) {
        int c = col[e];
        int r = row[e];
        int p = atomicAdd(&cursor[c], 1);
        epair[p] = make_int2(r, __float_as_int(dis[r]));
    }
}

// ---------------- h = x @ W (fp32 compute, bf16 store) ----------------
__global__ __launch_bounds__(256) void gemm_xw(const float* __restrict__ x,
                                               const float* __restrict__ W,
                                               unsigned* __restrict__ hb, int n) {
    __shared__ float xs[32][68];
    __shared__ float ws[32][128];
    int tid = threadIdx.x;
    int tx = tid & 31;
    int ty = tid >> 5;
    int row0 = blockIdx.x * 64;
    float acc[8][4] = {};

    for (int k0 = 0; k0 < 128; k0 += 32) {
        #pragma unroll
        for (int i = 0; i < 2; i++) {
            int li = tid + i * 256;
            int r = li >> 3;
            int kq = li & 7;
            int grow = row0 + r;
            if (grow >= n) grow = n - 1;
            float4 v = *(const float4*)&x[(size_t)grow * D + k0 + kq * 4];
            xs[kq * 4 + 0][r] = v.x;
            xs[kq * 4 + 1][r] = v.y;
            xs[kq * 4 + 2][r] = v.z;
            xs[kq * 4 + 3][r] = v.w;
        }
        #pragma unroll
        for (int i = 0; i < 4; i++) {
            int li = tid + i * 256;
            int c4 = li & 31;
            int k = li >> 5;
            *(float4*)&ws[k][c4 * 4] = *(const float4*)&W[(size_t)(k0 + k) * D + c4 * 4];
        }
        __syncthreads();
        #pragma unroll
        for (int k = 0; k < 32; k++) {
            float4 wv = *(const float4*)&ws[k][tx * 4];
            float xr[8];
            *(float4*)&xr[0] = *(const float4*)&xs[k][ty * 8];
            *(float4*)&xr[4] = *(const float4*)&xs[k][ty * 8 + 4];
            #pragma unroll
            for (int r = 0; r < 8; r++) {
                acc[r][0] += xr[r] * wv.x;
                acc[r][1] += xr[r] * wv.y;
                acc[r][2] += xr[r] * wv.z;
                acc[r][3] += xr[r] * wv.w;
            }
        }
        __syncthreads();
    }
    #pragma unroll
    for (int r = 0; r < 8; r++) {
        int gr = row0 + ty * 8 + r;
        if (gr < n) {
            uint2 pk;
            pk.x = bf16rne(acc[r][0]) | (bf16rne(acc[r][1]) << 16);
            pk.y = bf16rne(acc[r][2]) | (bf16rne(acc[r][3]) << 16);
            *(uint2*)&hb[(size_t)gr * 64 + tx * 2] = pk;
        }
    }
}

// ---------------- aggregation: wave per node, branch-free unroll-8, fused BN stats ----------------
__global__ __launch_bounds__(256) void aggregate(const unsigned* __restrict__ hb,
                                                 const float* __restrict__ dis,
                                                 const int* __restrict__ offsets,
                                                 const int2* __restrict__ epair,
                                                 const float* __restrict__ bias,
                                                 float* __restrict__ out,
                                                 float* __restrict__ gsum,
                                                 float* __restrict__ gsumsq, int n) {
    int tid = threadIdx.x;
    int wave = tid >> 6;
    int lane = tid & 63;
    float2 bv = *(const float2*)&bias[lane * 2];
    float s1a = 0.f, s1b = 0.f, s2a = 0.f, s2b = 0.f;

    for (int node = blockIdx.x * 4 + wave; node < n; node += gridDim.x * 4) {
        float dc = dis[node];
        int s0 = offsets[node], s1 = offsets[node + 1];
        int cnt = s1 - s0;
        unsigned hp = hb[(size_t)node * 64 + lane];
        float ax = dc * bflo(hp), ay = dc * bfhi(hp);
        // lane preload: masked lanes hold (node, 0.0) -> wasted loads hit the
        // self row (L1-resident) and multiply by 0. Branch-free inner loop.
        int2 ep = (lane < cnt) ? epair[s0 + lane] : make_int2(node, 0);
        int cap = cnt < 64 ? cnt : 64;
        int iters = (cap + 7) >> 3;
        for (int it = 0; it < iters; it++) {
            int base = it * 8;
            int sidx[8];
            float dv[8];
            #pragma unroll
            for (int j = 0; j < 8; j++) {
                sidx[j] = __shfl(ep.x, base + j);
                dv[j] = __int_as_float(__shfl(ep.y, base + j));
            }
            unsigned hv[8];
            #pragma unroll
            for (int j = 0; j < 8; j++) hv[j] = hb[(size_t)sidx[j] * 64 + lane];
            #pragma unroll
            for (int j = 0; j < 8; j++) {
                ax += dv[j] * bflo(hv[j]);
                ay += dv[j] * bfhi(hv[j]);
            }
        }
        for (int e = 64; e < cnt; e++) {  // rare deg>64 tail
            int2 q = epair[s0 + e];
            float dq = __int_as_float(q.y);
            unsigned hq = hb[(size_t)q.x * 64 + lane];
            ax += dq * bflo(hq);
            ay += dq * bfhi(hq);
        }
        float ox = dc * ax + bv.x;
        float oy = dc * ay + bv.y;
        *(float2*)&out[(size_t)node * D + lane * 2] = make_float2(ox, oy);
        s1a += ox; s1b += oy;
        s2a += ox * ox; s2b += oy * oy;
    }

    __shared__ float l1[4][128], l2[4][128];
    l1[wave][lane * 2] = s1a; l1[wave][lane * 2 + 1] = s1b;
    l2[wave][lane * 2] = s2a; l2[wave][lane * 2 + 1] = s2b;
    __syncthreads();
    if (tid < 128) {
        float a = l1[0][tid] + l1[1][tid] + l1[2][tid] + l1[3][tid];
        float b = l2[0][tid] + l2[1][tid] + l2[2][tid] + l2[3][tid];
        atomicAdd(&gsum[tid], a);
        atomicAdd(&gsumsq[tid], b);
    }
}

// ---------------- BN finalize + ReLU (in place, float4) ----------------
__global__ __launch_bounds__(256) void bn_finalize(float4* __restrict__ out4,
                                                   const float* __restrict__ gsum,
                                                   const float* __restrict__ gsumsq,
                                                   const float* __restrict__ gamma,
                                                   const float* __restrict__ beta,
                                                   int total4, float invN) {
    int i0 = blockIdx.x * 256 + threadIdx.x;
    int c = (i0 * 4) & 127;  // grid stride in floats is a multiple of 128
    float4 g4 = *(const float4*)&gsum[c];
    float4 q4 = *(const float4*)&gsumsq[c];
    float4 gm = *(const float4*)&gamma[c];
    float4 bt = *(const float4*)&beta[c];
    float m0 = g4.x * invN, m1 = g4.y * invN, m2 = g4.z * invN, m3 = g4.w * invN;
    float sc0 = rsqrtf(q4.x * invN - m0 * m0 + BN_EPS) * gm.x;
    float sc1 = rsqrtf(q4.y * invN - m1 * m1 + BN_EPS) * gm.y;
    float sc2 = rsqrtf(q4.z * invN - m2 * m2 + BN_EPS) * gm.z;
    float sc3 = rsqrtf(q4.w * invN - m3 * m3 + BN_EPS) * gm.w;
    float sh0 = bt.x - m0 * sc0, sh1 = bt.y - m1 * sc1;
    float sh2 = bt.z - m2 * sc2, sh3 = bt.w - m3 * sc3;
    for (int i = i0; i < total4; i += gridDim.x * 256) {
        float4 v = out4[i];
        v.x = fmaxf(fmaf(v.x, sc0, sh0), 0.f);
        v.y = fmaxf(fmaf(v.y, sc1, sh1), 0.f);
        v.z = fmaxf(fmaf(v.z, sc2, sh2), 0.f);
        v.w = fmaxf(fmaf(v.w, sc3, sh3), 0.f);
        out4[i] = v;
    }
}

extern "C" void kernel_launch(void* const* d_in, const int* in_sizes, int n_in,
                              void* d_out, int out_size, void* d_ws, size_t ws_size,
                              hipStream_t stream) {
    const float* x     = (const float*)d_in[0];
    const int*   pos   = (const int*)d_in[1];
    const float* W     = (const float*)d_in[3];
    const float* bias  = (const float*)d_in[4];
    const float* gamma = (const float*)d_in[5];
    const float* beta  = (const float*)d_in[6];
    float* out = (float*)d_out;

    int N  = in_sizes[0] / D;
    int EP = in_sizes[1] / 2;
    const int* prow = pos;
    const int* pcol = pos + EP;
    int nb = (N + 255) / 256;  // must be <= 256

    auto align = [](size_t v) { return (v + 255) & ~(size_t)255; };
    char* p = (char*)d_ws;
    int*      counts    = (int*)p;      p += align((size_t)N * 4);
    float*    gsum      = (float*)p;    p += align((size_t)D * 4);
    float*    gsumsq    = (float*)p;    p += align((size_t)D * 4);
    size_t zbytes = (size_t)(p - (char*)d_ws);
    float*    dis       = (float*)p;    p += align((size_t)N * 4);
    int*      offs      = (int*)p;      p += align(((size_t)N + 1) * 4);
    int*      cursor    = (int*)p;      p += align((size_t)N * 4);
    int*      blocksums = (int*)p;      p += align((size_t)256 * 4);
    int2*     epair     = (int2*)p;     p += align((size_t)EP * 8);
    unsigned* hb        = (unsigned*)p; p += align((size_t)N * 64 * 4);

    hipMemsetAsync(d_ws, 0, zbytes, stream);
    count_deg<<<(EP + 255) / 256, 256, 0, stream>>>(pcol, counts, EP);
    dis_scan_p1<<<nb, 256, 0, stream>>>(counts, dis, blocksums, N);
    scan_p3<<<nb, 256, 0, stream>>>(counts, blocksums, offs, cursor, N, nb);
    fill_csr<<<(EP + 255) / 256, 256, 0, stream>>>(prow, pcol, dis, cursor, epair, EP);
    gemm_xw<<<(N + 63) / 64, 256, 0, stream>>>(x, W, hb, N);
    aggregate<<<NB_AGG, 256, 0, stream>>>(hb, dis, offs, epair, bias, out, gsum, gsumsq, N);
    bn_finalize<<<1600, 256, 0, stream>>>((float4*)out, gsum, gsumsq, gamma, beta,
                                          N * D / 4, 1.0f / (float)N);
}

// Round 6
// 206.021 us; speedup vs baseline: 1.1833x; 1.1799x over previous
//
#include <hip/hip_runtime.h>

#define D 128
#define BN_EPS 1e-5f
#define NB_AGG 1024

__device__ __forceinline__ unsigned bf16rne(float f) {
    unsigned u = __float_as_uint(f);
    return (u + 0x7fffu + ((u >> 16) & 1u)) >> 16;
}
__device__ __forceinline__ float bflo(unsigned p) { return __uint_as_float(p << 16); }
__device__ __forceinline__ float bfhi(unsigned p) { return __uint_as_float(p & 0xffff0000u); }

// ---------------- degree count ----------------
__global__ void count_deg(const int* __restrict__ col, int* __restrict__ counts, int E) {
    int e = blockIdx.x * blockDim.x + threadIdx.x;
    if (e < E) atomicAdd(&counts[col[e]], 1);
}

// ---------------- dis + per-block sums (fused) ----------------
__global__ __launch_bounds__(256) void dis_scan_p1(const int* __restrict__ counts,
                                                   float* __restrict__ dis,
                                                   int* __restrict__ blocksums, int n) {
    __shared__ int lds[256];
    int tid = threadIdx.x;
    int i = blockIdx.x * 256 + tid;
    int c = (i < n) ? counts[i] : 0;
    if (i < n) dis[i] = rsqrtf((float)c + 1.0f);
    lds[tid] = c;
    __syncthreads();
    for (int d = 128; d > 0; d >>= 1) {
        if (tid < d) lds[tid] += lds[tid + d];
        __syncthreads();
    }
    if (tid == 0) blocksums[blockIdx.x] = lds[0];
}

// ---------------- fused: scan block sums in-block + local scan + offsets ----------------
__global__ __launch_bounds__(256) void scan_p3(const int* __restrict__ counts,
                                               const int* __restrict__ blocksums,
                                               int* __restrict__ offsets,
                                               int* __restrict__ cursor, int n, int nb) {
    __shared__ int bs[256];
    __shared__ int lds[256];
    int tid = threadIdx.x;
    bs[tid] = (tid < nb) ? blocksums[tid] : 0;
    __syncthreads();
    for (int d = 1; d < 256; d <<= 1) {
        int t = (tid >= d) ? bs[tid - d] : 0;
        __syncthreads();
        bs[tid] += t;
        __syncthreads();
    }
    int blockoff = (blockIdx.x == 0) ? 0 : bs[blockIdx.x - 1];
    int i = blockIdx.x * 256 + tid;
    int v = (i < n) ? counts[i] : 0;
    lds[tid] = v;
    __syncthreads();
    for (int d = 1; d < 256; d <<= 1) {
        int t = (tid >= d) ? lds[tid - d] : 0;
        __syncthreads();
        lds[tid] += t;
        __syncthreads();
    }
    if (i < n) {
        int off = blockoff + lds[tid] - v;
        offsets[i] = off;
        cursor[i] = off;
        if (i == n - 1) offsets[n] = off + v;
    }
}

// ---------------- CSR fill: (src, dis[src]) pairs sorted by dest ----------------
__global__ void fill_csr(const int* __restrict__ row, const int* __restrict__ col,
                         const float* __restrict__ dis, int* __restrict__ cursor,
                         int2* __restrict__ epair, int E) {
    int e = blockIdx.x * blockDim.x + threadIdx.x;
    if (e < E) {
        int c = col[e];
        int r = row[e];
        int p = atomicAdd(&cursor[c], 1);
        epair[p] = make_int2(r, __float_as_int(dis[r]));
    }
}

// ---------------- h = x @ W (fp32 compute, bf16 store) ----------------
__global__ __launch_bounds__(256) void gemm_xw(const float* __restrict__ x,
                                               const float* __restrict__ W,
                                               unsigned* __restrict__ hb, int n) {
    __shared__ float xs[32][68];
    __shared__ float ws[32][128];
    int tid = threadIdx.x;
    int tx = tid & 31;
    int ty = tid >> 5;
    int row0 = blockIdx.x * 64;
    float acc[8][4] = {};

    for (int k0 = 0; k0 < 128; k0 += 32) {
        #pragma unroll
        for (int i = 0; i < 2; i++) {
            int li = tid + i * 256;
            int r = li >> 3;
            int kq = li & 7;
            int grow = row0 + r;
            if (grow >= n) grow = n - 1;
            float4 v = *(const float4*)&x[(size_t)grow * D + k0 + kq * 4];
            xs[kq * 4 + 0][r] = v.x;
            xs[kq * 4 + 1][r] = v.y;
            xs[kq * 4 + 2][r] = v.z;
            xs[kq * 4 + 3][r] = v.w;
        }
        #pragma unroll
        for (int i = 0; i < 4; i++) {
            int li = tid + i * 256;
            int c4 = li & 31;
            int k = li >> 5;
            *(float4*)&ws[k][c4 * 4] = *(const float4*)&W[(size_t)(k0 + k) * D + c4 * 4];
        }
        __syncthreads();
        #pragma unroll
        for (int k = 0; k < 32; k++) {
            float4 wv = *(const float4*)&ws[k][tx * 4];
            float xr[8];
            *(float4*)&xr[0] = *(const float4*)&xs[k][ty * 8];
            *(float4*)&xr[4] = *(const float4*)&xs[k][ty * 8 + 4];
            #pragma unroll
            for (int r = 0; r < 8; r++) {
                acc[r][0] += xr[r] * wv.x;
                acc[r][1] += xr[r] * wv.y;
                acc[r][2] += xr[r] * wv.z;
                acc[r][3] += xr[r] * wv.w;
            }
        }
        __syncthreads();
    }
    #pragma unroll
    for (int r = 0; r < 8; r++) {
        int gr = row0 + ty * 8 + r;
        if (gr < n) {
            uint2 pk;
            pk.x = bf16rne(acc[r][0]) | (bf16rne(acc[r][1]) << 16);
            pk.y = bf16rne(acc[r][2]) | (bf16rne(acc[r][3]) << 16);
            *(uint2*)&hb[(size_t)gr * 64 + tx * 2] = pk;
        }
    }
}

// ---------------- aggregation: wave/node, unroll-4, partials out (no atomic tail) ----------------
__global__ __launch_bounds__(512) void aggregate(const unsigned* __restrict__ hb,
                                                 const float* __restrict__ dis,
                                                 const int* __restrict__ offsets,
                                                 const int2* __restrict__ epair,
                                                 const float* __restrict__ bias,
                                                 float* __restrict__ out,
                                                 float* __restrict__ partials, int n) {
    int tid = threadIdx.x;
    int wave = tid >> 6;      // 0..7
    int lane = tid & 63;
    float2 bv = *(const float2*)&bias[lane * 2];
    float s1a = 0.f, s1b = 0.f, s2a = 0.f, s2b = 0.f;

    for (int node = blockIdx.x * 8 + wave; node < n; node += gridDim.x * 8) {
        float dc = dis[node];
        int s0 = offsets[node], s1 = offsets[node + 1];
        int cnt = s1 - s0;
        unsigned hp = hb[(size_t)node * 64 + lane];
        float ax = dc * bflo(hp), ay = dc * bfhi(hp);
        int2 ep = (lane < cnt) ? epair[s0 + lane] : make_int2(0, 0);
        int cap = cnt < 64 ? cnt : 64;
        int e = 0;
        for (; e + 4 <= cap; e += 4) {
            int sA = __shfl(ep.x, e), sB = __shfl(ep.x, e + 1);
            int sC = __shfl(ep.x, e + 2), sD = __shfl(ep.x, e + 3);
            float dA = __int_as_float(__shfl(ep.y, e));
            float dB = __int_as_float(__shfl(ep.y, e + 1));
            float dC = __int_as_float(__shfl(ep.y, e + 2));
            float dD = __int_as_float(__shfl(ep.y, e + 3));
            unsigned hA = hb[(size_t)sA * 64 + lane];
            unsigned hB = hb[(size_t)sB * 64 + lane];
            unsigned hC = hb[(size_t)sC * 64 + lane];
            unsigned hD = hb[(size_t)sD * 64 + lane];
            ax += dA * bflo(hA); ay += dA * bfhi(hA);
            ax += dB * bflo(hB); ay += dB * bfhi(hB);
            ax += dC * bflo(hC); ay += dC * bfhi(hC);
            ax += dD * bflo(hD); ay += dD * bfhi(hD);
        }
        for (; e < cap; e++) {
            int s = __shfl(ep.x, e);
            float dv = __int_as_float(__shfl(ep.y, e));
            unsigned hq = hb[(size_t)s * 64 + lane];
            ax += dv * bflo(hq); ay += dv * bfhi(hq);
        }
        for (e = 64; e < cnt; e++) {  // rare deg>64 tail
            int2 q = epair[s0 + e];
            float dq = __int_as_float(q.y);
            unsigned hq = hb[(size_t)q.x * 64 + lane];
            ax += dq * bflo(hq); ay += dq * bfhi(hq);
        }
        float ox = dc * ax + bv.x;
        float oy = dc * ay + bv.y;
        *(float2*)&out[(size_t)node * D + lane * 2] = make_float2(ox, oy);
        s1a += ox; s1b += oy;
        s2a += ox * ox; s2b += oy * oy;
    }

    // 8-wave LDS reduce, then one coalesced 1 KB partial write per block (no atomics)
    __shared__ float l1[8][128], l2[8][128];
    l1[wave][lane * 2] = s1a; l1[wave][lane * 2 + 1] = s1b;
    l2[wave][lane * 2] = s2a; l2[wave][lane * 2 + 1] = s2b;
    __syncthreads();
    if (tid < 256) {
        int col = tid & 127;
        float v;
        if (tid < 128) {
            v = l1[0][col] + l1[1][col] + l1[2][col] + l1[3][col] +
                l1[4][col] + l1[5][col] + l1[6][col] + l1[7][col];
        } else {
            v = l2[0][col] + l2[1][col] + l2[2][col] + l2[3][col] +
                l2[4][col] + l2[5][col] + l2[6][col] + l2[7][col];
        }
        partials[(size_t)blockIdx.x * 256 + tid] = v;
    }
}

// ---------------- fold partials [NB_AGG][256] into gsum/gsumsq ----------------
__global__ __launch_bounds__(256) void bn_reduce(const float* __restrict__ partials,
                                                 float* __restrict__ gsum,
                                                 float* __restrict__ gsumsq, int nrows) {
    int tid = threadIdx.x;
    float s = 0.f;
    for (int r = blockIdx.x; r < nrows; r += gridDim.x)
        s += partials[(size_t)r * 256 + tid];
    if (tid < 128) atomicAdd(&gsum[tid], s);
    else           atomicAdd(&gsumsq[tid - 128], s);
}

// ---------------- BN finalize + ReLU (in place, float4) ----------------
__global__ __launch_bounds__(256) void bn_finalize(float4* __restrict__ out4,
                                                   const float* __restrict__ gsum,
                                                   const float* __restrict__ gsumsq,
                                                   const float* __restrict__ gamma,
                                                   const float* __restrict__ beta,
                                                   int total4, float invN) {
    int i0 = blockIdx.x * 256 + threadIdx.x;
    int c = (i0 * 4) & 127;  // grid stride in floats is a multiple of 128
    float4 g4 = *(const float4*)&gsum[c];
    float4 q4 = *(const float4*)&gsumsq[c];
    float4 gm = *(const float4*)&gamma[c];
    float4 bt = *(const float4*)&beta[c];
    float m0 = g4.x * invN, m1 = g4.y * invN, m2 = g4.z * invN, m3 = g4.w * invN;
    float sc0 = rsqrtf(q4.x * invN - m0 * m0 + BN_EPS) * gm.x;
    float sc1 = rsqrtf(q4.y * invN - m1 * m1 + BN_EPS) * gm.y;
    float sc2 = rsqrtf(q4.z * invN - m2 * m2 + BN_EPS) * gm.z;
    float sc3 = rsqrtf(q4.w * invN - m3 * m3 + BN_EPS) * gm.w;
    float sh0 = bt.x - m0 * sc0, sh1 = bt.y - m1 * sc1;
    float sh2 = bt.z - m2 * sc2, sh3 = bt.w - m3 * sc3;
    for (int i = i0; i < total4; i += gridDim.x * 256) {
        float4 v = out4[i];
        v.x = fmaxf(fmaf(v.x, sc0, sh0), 0.f);
        v.y = fmaxf(fmaf(v.y, sc1, sh1), 0.f);
        v.z = fmaxf(fmaf(v.z, sc2, sh2), 0.f);
        v.w = fmaxf(fmaf(v.w, sc3, sh3), 0.f);
        out4[i] = v;
    }
}

extern "C" void kernel_launch(void* const* d_in, const int* in_sizes, int n_in,
                              void* d_out, int out_size, void* d_ws, size_t ws_size,
                              hipStream_t stream) {
    const float* x     = (const float*)d_in[0];
    const int*   pos   = (const int*)d_in[1];
    const float* W     = (const float*)d_in[3];
    const float* bias  = (const float*)d_in[4];
    const float* gamma = (const float*)d_in[5];
    const float* beta  = (const float*)d_in[6];
    float* out = (float*)d_out;

    int N  = in_sizes[0] / D;
    int EP = in_sizes[1] / 2;
    const int* prow = pos;
    const int* pcol = pos + EP;
    int nb = (N + 255) / 256;  // must be <= 256

    auto align = [](size_t v) { return (v + 255) & ~(size_t)255; };
    char* p = (char*)d_ws;
    int*      counts    = (int*)p;      p += align((size_t)N * 4);
    float*    gsum      = (float*)p;    p += align((size_t)D * 4);
    float*    gsumsq    = (float*)p;    p += align((size_t)D * 4);
    size_t zbytes = (size_t)(p - (char*)d_ws);
    float*    dis       = (float*)p;    p += align((size_t)N * 4);
    int*      offs      = (int*)p;      p += align(((size_t)N + 1) * 4);
    int*      cursor    = (int*)p;      p += align((size_t)N * 4);
    int*      blocksums = (int*)p;      p += align((size_t)256 * 4);
    int2*     epair     = (int2*)p;     p += align((size_t)EP * 8);
    unsigned* hb        = (unsigned*)p; p += align((size_t)N * 64 * 4);
    float*    partials  = (float*)p;    p += align((size_t)NB_AGG * 256 * 4);

    hipMemsetAsync(d_ws, 0, zbytes, stream);
    count_deg<<<(EP + 255) / 256, 256, 0, stream>>>(pcol, counts, EP);
    dis_scan_p1<<<nb, 256, 0, stream>>>(counts, dis, blocksums, N);
    scan_p3<<<nb, 256, 0, stream>>>(counts, blocksums, offs, cursor, N, nb);
    fill_csr<<<(EP + 255) / 256, 256, 0, stream>>>(prow, pcol, dis, cursor, epair, EP);
    gemm_xw<<<(N + 63) / 64, 256, 0, stream>>>(x, W, hb, N);
    aggregate<<<NB_AGG, 512, 0, stream>>>(hb, dis, offs, epair, bias, out, partials, N);
    bn_reduce<<<64, 256, 0, stream>>>(partials, gsum, gsumsq, NB_AGG);
    bn_finalize<<<1600, 256, 0, stream>>>((float4*)out, gsum, gsumsq, gamma, beta,
                                          N * D / 4, 1.0f / (float)N);
}

// Round 8
// 178.759 us; speedup vs baseline: 1.3637x; 1.1525x over previous
//
#include <hip/hip_runtime.h>

#define D 128
#define BN_EPS 1e-5f
#define K_ELL 40
#define NB_AGG 1024

__device__ __forceinline__ unsigned bf16rne(float f) {
    unsigned u = __float_as_uint(f);
    return (u + 0x7fffu + ((u >> 16) & 1u)) >> 16;
}
__device__ __forceinline__ float bflo(unsigned p) { return __uint_as_float(p << 16); }
__device__ __forceinline__ float bfhi(unsigned p) { return __uint_as_float(p & 0xffff0000u); }

// ---------------- one-pass degree count + ELL fill ----------------
__global__ void count_fill(const int* __restrict__ prow, const int* __restrict__ pcol,
                           int* __restrict__ deg, int* __restrict__ ell,
                           int2* __restrict__ ovf, int* __restrict__ ovf_cnt, int E) {
    int e = blockIdx.x * blockDim.x + threadIdx.x;
    if (e < E) {
        int c = pcol[e];
        int r = prow[e];
        int p = atomicAdd(&deg[c], 1);
        if (p < K_ELL) {
            ell[c * K_ELL + p] = r;
        } else {  // statistically never at deg~Poisson(10); correctness-safe
            int q = atomicAdd(ovf_cnt, 1);
            ovf[q] = make_int2(c, r);
        }
    }
}

// ---------------- h = x @ W (fp32 compute, bf16 store) + dis prologue ----------------
__global__ __launch_bounds__(256) void gemm_xw(const float* __restrict__ x,
                                               const float* __restrict__ W,
                                               const int* __restrict__ deg,
                                               float* __restrict__ dis,
                                               unsigned* __restrict__ hb, int n) {
    __shared__ float xs[32][68];
    __shared__ float ws[32][128];
    int tid = threadIdx.x;
    int tx = tid & 31;
    int ty = tid >> 5;
    int row0 = blockIdx.x * 64;

    // fused dis = rsqrt(deg+1) for this block's 64 rows
    if (tid < 64) {
        int gr = row0 + tid;
        if (gr < n) dis[gr] = rsqrtf((float)deg[gr] + 1.0f);
    }

    float acc[8][4] = {};
    for (int k0 = 0; k0 < 128; k0 += 32) {
        #pragma unroll
        for (int i = 0; i < 2; i++) {
            int li = tid + i * 256;
            int r = li >> 3;
            int kq = li & 7;
            int grow = row0 + r;
            if (grow >= n) grow = n - 1;
            float4 v = *(const float4*)&x[(size_t)grow * D + k0 + kq * 4];
            xs[kq * 4 + 0][r] = v.x;
            xs[kq * 4 + 1][r] = v.y;
            xs[kq * 4 + 2][r] = v.z;
            xs[kq * 4 + 3][r] = v.w;
        }
        #pragma unroll
        for (int i = 0; i < 4; i++) {
            int li = tid + i * 256;
            int c4 = li & 31;
            int k = li >> 5;
            *(float4*)&ws[k][c4 * 4] = *(const float4*)&W[(size_t)(k0 + k) * D + c4 * 4];
        }
        __syncthreads();
        #pragma unroll
        for (int k = 0; k < 32; k++) {
            float4 wv = *(const float4*)&ws[k][tx * 4];
            float xr[8];
            *(float4*)&xr[0] = *(const float4*)&xs[k][ty * 8];
            *(float4*)&xr[4] = *(const float4*)&xs[k][ty * 8 + 4];
            #pragma unroll
            for (int r = 0; r < 8; r++) {
                acc[r][0] += xr[r] * wv.x;
                acc[r][1] += xr[r] * wv.y;
                acc[r][2] += xr[r] * wv.z;
                acc[r][3] += xr[r] * wv.w;
            }
        }
        __syncthreads();
    }
    #pragma unroll
    for (int r = 0; r < 8; r++) {
        int gr = row0 + ty * 8 + r;
        if (gr < n) {
            uint2 pk;
            pk.x = bf16rne(acc[r][0]) | (bf16rne(acc[r][1]) << 16);
            pk.y = bf16rne(acc[r][2]) | (bf16rne(acc[r][3]) << 16);
            *(uint2*)&hb[(size_t)gr * 64 + tx * 2] = pk;
        }
    }
}

// ---------------- aggregation: wave/node, ELL gather, unroll-4, partials out ----------------
__global__ __launch_bounds__(512) void aggregate(const unsigned* __restrict__ hb,
                                                 const float* __restrict__ dis,
                                                 const int* __restrict__ deg,
                                                 const int* __restrict__ ell,
                                                 const int2* __restrict__ ovf,
                                                 const int* __restrict__ ovf_cnt,
                                                 const float* __restrict__ bias,
                                                 float* __restrict__ out,
                                                 float* __restrict__ partials, int n) {
    int tid = threadIdx.x;
    int wave = tid >> 6;      // 0..7
    int lane = tid & 63;
    float2 bv = *(const float2*)&bias[lane * 2];
    float s1a = 0.f, s1b = 0.f, s2a = 0.f, s2b = 0.f;

    for (int node = blockIdx.x * 8 + wave; node < n; node += gridDim.x * 8) {
        float dc = dis[node];
        int cntT = deg[node];
        int cntE = cntT < K_ELL ? cntT : K_ELL;
        unsigned hp = hb[(size_t)node * 64 + lane];
        float ax = dc * bflo(hp), ay = dc * bfhi(hp);
        // lane preload of this node's ELL slots: src then dis[src] (once per node)
        int es = (lane < cntE) ? ell[node * K_ELL + lane] : 0;
        float ed = (lane < cntE) ? dis[es] : 0.f;
        int e = 0;
        for (; e + 4 <= cntE; e += 4) {
            int sA = __shfl(es, e), sB = __shfl(es, e + 1);
            int sC = __shfl(es, e + 2), sD = __shfl(es, e + 3);
            float dA = __shfl(ed, e), dB = __shfl(ed, e + 1);
            float dC = __shfl(ed, e + 2), dD = __shfl(ed, e + 3);
            unsigned hA = hb[(size_t)sA * 64 + lane];
            unsigned hB = hb[(size_t)sB * 64 + lane];
            unsigned hC = hb[(size_t)sC * 64 + lane];
            unsigned hD = hb[(size_t)sD * 64 + lane];
            ax += dA * bflo(hA); ay += dA * bfhi(hA);
            ax += dB * bflo(hB); ay += dB * bfhi(hB);
            ax += dC * bflo(hC); ay += dC * bfhi(hC);
            ax += dD * bflo(hD); ay += dD * bfhi(hD);
        }
        for (; e < cntE; e++) {
            int s = __shfl(es, e);
            float dv = __shfl(ed, e);
            unsigned hq = hb[(size_t)s * 64 + lane];
            ax += dv * bflo(hq); ay += dv * bfhi(hq);
        }
        if (cntT > K_ELL) {  // overflow scan (practically never taken)
            int novf = *ovf_cnt;
            for (int j = 0; j < novf; j++) {
                int2 q = ovf[j];
                if (q.x == node) {
                    float dv = dis[q.y];
                    unsigned hq = hb[(size_t)q.y * 64 + lane];
                    ax += dv * bflo(hq); ay += dv * bfhi(hq);
                }
            }
        }
        float ox = dc * ax + bv.x;
        float oy = dc * ay + bv.y;
        *(float2*)&out[(size_t)node * D + lane * 2] = make_float2(ox, oy);
        s1a += ox; s1b += oy;
        s2a += ox * ox; s2b += oy * oy;
    }

    // 8-wave LDS reduce, one coalesced 1 KB partial write per block (no atomics)
    __shared__ float l1[8][128], l2[8][128];
    l1[wave][lane * 2] = s1a; l1[wave][lane * 2 + 1] = s1b;
    l2[wave][lane * 2] = s2a; l2[wave][lane * 2 + 1] = s2b;
    __syncthreads();
    if (tid < 256) {
        int col = tid & 127;
        float v;
        if (tid < 128) {
            v = l1[0][col] + l1[1][col] + l1[2][col] + l1[3][col] +
                l1[4][col] + l1[5][col] + l1[6][col] + l1[7][col];
        } else {
            v = l2[0][col] + l2[1][col] + l2[2][col] + l2[3][col] +
                l2[4][col] + l2[5][col] + l2[6][col] + l2[7][col];
        }
        partials[(size_t)blockIdx.x * 256 + tid] = v;
    }
}

// ---------------- fold partials [NB_AGG][256] into gsum/gsumsq ----------------
__global__ __launch_bounds__(256) void bn_reduce(const float* __restrict__ partials,
                                                 float* __restrict__ gsum,
                                                 float* __restrict__ gsumsq, int nrows) {
    int tid = threadIdx.x;
    float s = 0.f;
    for (int r = blockIdx.x; r < nrows; r += gridDim.x)
        s += partials[(size_t)r * 256 + tid];
    if (tid < 128) atomicAdd(&gsum[tid], s);
    else           atomicAdd(&gsumsq[tid - 128], s);
}

// ---------------- BN finalize + ReLU (in place, float4) ----------------
__global__ __launch_bounds__(256) void bn_finalize(float4* __restrict__ out4,
                                                   const float* __restrict__ gsum,
                                                   const float* __restrict__ gsumsq,
                                                   const float* __restrict__ gamma,
                                                   const float* __restrict__ beta,
                                                   int total4, float invN) {
    int i0 = blockIdx.x * 256 + threadIdx.x;
    int c = (i0 * 4) & 127;  // grid stride in floats is a multiple of 128
    float4 g4 = *(const float4*)&gsum[c];
    float4 q4 = *(const float4*)&gsumsq[c];
    float4 gm = *(const float4*)&gamma[c];
    float4 bt = *(const float4*)&beta[c];
    float m0 = g4.x * invN, m1 = g4.y * invN, m2 = g4.z * invN, m3 = g4.w * invN;
    float sc0 = rsqrtf(q4.x * invN - m0 * m0 + BN_EPS) * gm.x;
    float sc1 = rsqrtf(q4.y * invN - m1 * m1 + BN_EPS) * gm.y;
    float sc2 = rsqrtf(q4.z * invN - m2 * m2 + BN_EPS) * gm.z;
    float sc3 = rsqrtf(q4.w * invN - m3 * m3 + BN_EPS) * gm.w;
    float sh0 = bt.x - m0 * sc0, sh1 = bt.y - m1 * sc1;
    float sh2 = bt.z - m2 * sc2, sh3 = bt.w - m3 * sc3;
    for (int i = i0; i < total4; i += gridDim.x * 256) {
        float4 v = out4[i];
        v.x = fmaxf(fmaf(v.x, sc0, sh0), 0.f);
        v.y = fmaxf(fmaf(v.y, sc1, sh1), 0.f);
        v.z = fmaxf(fmaf(v.z, sc2, sh2), 0.f);
        v.w = fmaxf(fmaf(v.w, sc3, sh3), 0.f);
        out4[i] = v;
    }
}

extern "C" void kernel_launch(void* const* d_in, const int* in_sizes, int n_in,
                              void* d_out, int out_size, void* d_ws, size_t ws_size,
                              hipStream_t stream) {
    const float* x     = (const float*)d_in[0];
    const int*   pos   = (const int*)d_in[1];
    const float* W     = (const float*)d_in[3];
    const float* bias  = (const float*)d_in[4];
    const float* gamma = (const float*)d_in[5];
    const float* beta  = (const float*)d_in[6];
    float* out = (float*)d_out;

    int N  = in_sizes[0] / D;
    int EP = in_sizes[1] / 2;
    const int* prow = pos;
    const int* pcol = pos + EP;

    auto align = [](size_t v) { return (v + 255) & ~(size_t)255; };
    char* p = (char*)d_ws;
    // ---- zeroed region (one memset): deg, ovf_cnt, gsum, gsumsq ----
    int*      deg     = (int*)p;      p += align((size_t)N * 4);
    int*      ovf_cnt = (int*)p;      p += align(256);
    float*    gsum    = (float*)p;    p += align((size_t)D * 4);
    float*    gsumsq  = (float*)p;    p += align((size_t)D * 4);
    size_t zbytes = (size_t)(p - (char*)d_ws);
    // ---- rest ----
    float*    dis      = (float*)p;    p += align((size_t)N * 4);
    int*      ell      = (int*)p;      p += align((size_t)N * K_ELL * 4);
    int2*     ovf      = (int2*)p;     p += align((size_t)EP * 8);
    unsigned* hb       = (unsigned*)p; p += align((size_t)N * 64 * 4);
    float*    partials = (float*)p;    p += align((size_t)NB_AGG * 256 * 4);

    hipMemsetAsync(d_ws, 0, zbytes, stream);
    count_fill<<<(EP + 255) / 256, 256, 0, stream>>>(prow, pcol, deg, ell, ovf, ovf_cnt, EP);
    gemm_xw<<<(N + 63) / 64, 256, 0, stream>>>(x, W, deg, dis, hb, N);
    aggregate<<<NB_AGG, 512, 0, stream>>>(hb, dis, deg, ell, ovf, ovf_cnt, bias, out,
                                          partials, N);
    bn_reduce<<<64, 256, 0, stream>>>(partials, gsum, gsumsq, NB_AGG);
    bn_finalize<<<1600, 256, 0, stream>>>((float4*)out, gsum, gsumsq, gamma, beta,
                                          N * D / 4, 1.0f / (float)N);
}

// Round 9
// 158.670 us; speedup vs baseline: 1.5364x; 1.1266x over previous
//
#include <hip/hip_runtime.h>

#define D 128
#define BN_EPS 1e-5f
#define K_ELL 40
#define NB_AGG 1024

typedef __attribute__((ext_vector_type(8))) short bf16x8;
typedef __attribute__((ext_vector_type(4))) float f32x4;

__device__ __forceinline__ unsigned bf16rne(float f) {
    unsigned u = __float_as_uint(f);
    return (u + 0x7fffu + ((u >> 16) & 1u)) >> 16;
}
__device__ __forceinline__ float bflo(unsigned p) { return __uint_as_float(p << 16); }
__device__ __forceinline__ float bfhi(unsigned p) { return __uint_as_float(p & 0xffff0000u); }

// ---------------- prep: degree count + ELL fill + W -> bf16 transpose ----------------
__global__ void prep(const int* __restrict__ prow, const int* __restrict__ pcol,
                     int* __restrict__ deg, int* __restrict__ ell,
                     int2* __restrict__ ovf, int* __restrict__ ovf_cnt,
                     const float* __restrict__ W, ushort* __restrict__ wbT, int E) {
    int gtid = blockIdx.x * blockDim.x + threadIdx.x;
    int gsz = gridDim.x * blockDim.x;
    // wbT[c][k] = bf16(W[k][c])  (coalesced read, scattered 2B write; 16K elems once)
    for (int i = gtid; i < D * D; i += gsz) {
        int k = i >> 7, c = i & 127;
        wbT[c * D + k] = (ushort)bf16rne(W[i]);
    }
    for (int e = gtid; e < E; e += gsz) {
        int c = pcol[e];
        int r = prow[e];
        int p = atomicAdd(&deg[c], 1);
        if (p < K_ELL) {
            ell[c * K_ELL + p] = r;
        } else {  // statistically never at deg~Poisson(10); correctness-safe
            int q = atomicAdd(ovf_cnt, 1);
            ovf[q] = make_int2(c, r);
        }
    }
}

// ---------------- h = x @ W via bf16 MFMA (64x128 block tile, 4 waves) ----------------
__global__ __launch_bounds__(256) void gemm_mfma(const float* __restrict__ x,
                                                 const ushort* __restrict__ wbT,
                                                 ushort* __restrict__ hb, int n) {
    __shared__ ushort xsb[64][136];   // [row][k], +16B pad -> 2-way (free) bank access
    __shared__ ushort wsb[128][136];  // [col][k]
    int tid = threadIdx.x;
    int wave = tid >> 6;
    int lane = tid & 63;
    int row0 = blockIdx.x * 64;

    // stage W (bf16, already transposed): 2048 x 16B
    #pragma unroll
    for (int i = 0; i < 8; i++) {
        int flat = i * 256 + tid;      // 0..2047
        int c = flat >> 4, seg = flat & 15;
        *(uint4*)&wsb[c][seg * 8] = ((const uint4*)wbT)[flat];
    }
    // stage x tile, fp32 -> bf16
    {
        int r = tid >> 2, kq = tid & 3;
        int grow = row0 + r;
        if (grow >= n) grow = n - 1;
        const float4* src = (const float4*)&x[(size_t)grow * D + kq * 32];
        uint* dst = (uint*)&xsb[r][kq * 32];
        #pragma unroll
        for (int q = 0; q < 8; q++) {
            float4 v = src[q];
            dst[q * 2]     = bf16rne(v.x) | (bf16rne(v.y) << 16);
            dst[q * 2 + 1] = bf16rne(v.z) | (bf16rne(v.w) << 16);
        }
    }
    __syncthreads();

    f32x4 acc[4][2];
    #pragma unroll
    for (int mt = 0; mt < 4; mt++)
        #pragma unroll
        for (int nt = 0; nt < 2; nt++)
            acc[mt][nt] = (f32x4){0.f, 0.f, 0.f, 0.f};

    int ar = lane & 15;            // A row / B col within 16-tile
    int ako = (lane >> 4) * 8;     // k offset within K=32 chunk
    #pragma unroll
    for (int k0 = 0; k0 < 128; k0 += 32) {
        bf16x8 a[4], b[2];
        #pragma unroll
        for (int mt = 0; mt < 4; mt++)
            a[mt] = *(const bf16x8*)&xsb[mt * 16 + ar][k0 + ako];
        #pragma unroll
        for (int nt = 0; nt < 2; nt++)
            b[nt] = *(const bf16x8*)&wsb[wave * 32 + nt * 16 + ar][k0 + ako];
        #pragma unroll
        for (int mt = 0; mt < 4; mt++)
            #pragma unroll
            for (int nt = 0; nt < 2; nt++)
                acc[mt][nt] = __builtin_amdgcn_mfma_f32_16x16x32_bf16(
                    a[mt], b[nt], acc[mt][nt], 0, 0, 0);
    }

    // store: D col=lane&15, row=(lane>>4)*4+reg  [m89-verified]
    int col = lane & 15, rq = (lane >> 4) * 4;
    #pragma unroll
    for (int mt = 0; mt < 4; mt++) {
        #pragma unroll
        for (int r = 0; r < 4; r++) {
            int grow = row0 + mt * 16 + rq + r;
            if (grow < n) {
                #pragma unroll
                for (int nt = 0; nt < 2; nt++)
                    hb[(size_t)grow * D + wave * 32 + nt * 16 + col] =
                        (ushort)bf16rne(acc[mt][nt][r]);
            }
        }
    }
}

// ---------------- aggregation: wave/node, ELL gather, unroll-4, partials out ----------------
__global__ __launch_bounds__(512) void aggregate(const unsigned* __restrict__ hb,
                                                 const int* __restrict__ deg,
                                                 const int* __restrict__ ell,
                                                 const int2* __restrict__ ovf,
                                                 const int* __restrict__ ovf_cnt,
                                                 const float* __restrict__ bias,
                                                 float* __restrict__ out,
                                                 float* __restrict__ partials, int n) {
    int tid = threadIdx.x;
    int wave = tid >> 6;      // 0..7
    int lane = tid & 63;
    float2 bv = *(const float2*)&bias[lane * 2];
    float s1a = 0.f, s1b = 0.f, s2a = 0.f, s2b = 0.f;

    for (int node = blockIdx.x * 8 + wave; node < n; node += gridDim.x * 8) {
        int cntT = deg[node];
        float dc = rsqrtf((float)cntT + 1.0f);
        int cntE = cntT < K_ELL ? cntT : K_ELL;
        unsigned hp = hb[(size_t)node * 64 + lane];
        float ax = dc * bflo(hp), ay = dc * bfhi(hp);
        int es = (lane < cntE) ? ell[node * K_ELL + lane] : 0;
        float ed = (lane < cntE) ? rsqrtf((float)deg[es] + 1.0f) : 0.f;
        int e = 0;
        for (; e + 4 <= cntE; e += 4) {
            int sA = __shfl(es, e), sB = __shfl(es, e + 1);
            int sC = __shfl(es, e + 2), sD = __shfl(es, e + 3);
            float dA = __shfl(ed, e), dB = __shfl(ed, e + 1);
            float dC = __shfl(ed, e + 2), dD = __shfl(ed, e + 3);
            unsigned hA = hb[(size_t)sA * 64 + lane];
            unsigned hB = hb[(size_t)sB * 64 + lane];
            unsigned hC = hb[(size_t)sC * 64 + lane];
            unsigned hD = hb[(size_t)sD * 64 + lane];
            ax += dA * bflo(hA); ay += dA * bfhi(hA);
            ax += dB * bflo(hB); ay += dB * bfhi(hB);
            ax += dC * bflo(hC); ay += dC * bfhi(hC);
            ax += dD * bflo(hD); ay += dD * bfhi(hD);
        }
        for (; e < cntE; e++) {
            int s = __shfl(es, e);
            float dv = __shfl(ed, e);
            unsigned hq = hb[(size_t)s * 64 + lane];
            ax += dv * bflo(hq); ay += dv * bfhi(hq);
        }
        if (cntT > K_ELL) {  // overflow scan (practically never taken)
            int novf = *ovf_cnt;
            for (int j = 0; j < novf; j++) {
                int2 q = ovf[j];
                if (q.x == node) {
                    float dv = rsqrtf((float)deg[q.y] + 1.0f);
                    unsigned hq = hb[(size_t)q.y * 64 + lane];
                    ax += dv * bflo(hq); ay += dv * bfhi(hq);
                }
            }
        }
        float ox = dc * ax + bv.x;
        float oy = dc * ay + bv.y;
        *(float2*)&out[(size_t)node * D + lane * 2] = make_float2(ox, oy);
        s1a += ox; s1b += oy;
        s2a += ox * ox; s2b += oy * oy;
    }

    // 8-wave LDS reduce, one coalesced 1 KB partial write per block (no atomics)
    __shared__ float l1[8][128], l2[8][128];
    l1[wave][lane * 2] = s1a; l1[wave][lane * 2 + 1] = s1b;
    l2[wave][lane * 2] = s2a; l2[wave][lane * 2 + 1] = s2b;
    __syncthreads();
    if (tid < 256) {
        int col = tid & 127;
        float v;
        if (tid < 128) {
            v = l1[0][col] + l1[1][col] + l1[2][col] + l1[3][col] +
                l1[4][col] + l1[5][col] + l1[6][col] + l1[7][col];
        } else {
            v = l2[0][col] + l2[1][col] + l2[2][col] + l2[3][col] +
                l2[4][col] + l2[5][col] + l2[6][col] + l2[7][col];
        }
        partials[(size_t)blockIdx.x * 256 + tid] = v;
    }
}

// ---------------- fold partials [NB_AGG][256] into gsum/gsumsq ----------------
__global__ __launch_bounds__(256) void bn_reduce(const float* __restrict__ partials,
                                                 float* __restrict__ gsum,
                                                 float* __restrict__ gsumsq, int nrows) {
    int tid = threadIdx.x;
    float s = 0.f;
    for (int r = blockIdx.x; r < nrows; r += gridDim.x)
        s += partials[(size_t)r * 256 + tid];
    if (tid < 128) atomicAdd(&gsum[tid], s);
    else           atomicAdd(&gsumsq[tid - 128], s);
}

// ---------------- BN finalize + ReLU (in place, float4) ----------------
__global__ __launch_bounds__(256) void bn_finalize(float4* __restrict__ out4,
                                                   const float* __restrict__ gsum,
                                                   const float* __restrict__ gsumsq,
                                                   const float* __restrict__ gamma,
                                                   const float* __restrict__ beta,
                                                   int total4, float invN) {
    int i0 = blockIdx.x * 256 + threadIdx.x;
    int c = (i0 * 4) & 127;  // grid stride in floats is a multiple of 128
    float4 g4 = *(const float4*)&gsum[c];
    float4 q4 = *(const float4*)&gsumsq[c];
    float4 gm = *(const float4*)&gamma[c];
    float4 bt = *(const float4*)&beta[c];
    float m0 = g4.x * invN, m1 = g4.y * invN, m2 = g4.z * invN, m3 = g4.w * invN;
    float sc0 = rsqrtf(q4.x * invN - m0 * m0 + BN_EPS) * gm.x;
    float sc1 = rsqrtf(q4.y * invN - m1 * m1 + BN_EPS) * gm.y;
    float sc2 = rsqrtf(q4.z * invN - m2 * m2 + BN_EPS) * gm.z;
    float sc3 = rsqrtf(q4.w * invN - m3 * m3 + BN_EPS) * gm.w;
    float sh0 = bt.x - m0 * sc0, sh1 = bt.y - m1 * sc1;
    float sh2 = bt.z - m2 * sc2, sh3 = bt.w - m3 * sc3;
    for (int i = i0; i < total4; i += gridDim.x * 256) {
        float4 v = out4[i];
        v.x = fmaxf(fmaf(v.x, sc0, sh0), 0.f);
        v.y = fmaxf(fmaf(v.y, sc1, sh1), 0.f);
        v.z = fmaxf(fmaf(v.z, sc2, sh2), 0.f);
        v.w = fmaxf(fmaf(v.w, sc3, sh3), 0.f);
        out4[i] = v;
    }
}

extern "C" void kernel_launch(void* const* d_in, const int* in_sizes, int n_in,
                              void* d_out, int out_size, void* d_ws, size_t ws_size,
                              hipStream_t stream) {
    const float* x     = (const float*)d_in[0];
    const int*   pos   = (const int*)d_in[1];
    const float* W     = (const float*)d_in[3];
    const float* bias  = (const float*)d_in[4];
    const float* gamma = (const float*)d_in[5];
    const float* beta  = (const float*)d_in[6];
    float* out = (float*)d_out;

    int N  = in_sizes[0] / D;
    int EP = in_sizes[1] / 2;
    const int* prow = pos;
    const int* pcol = pos + EP;

    auto align = [](size_t v) { return (v + 255) & ~(size_t)255; };
    char* p = (char*)d_ws;
    // ---- zeroed region (one memset): deg, ovf_cnt, gsum, gsumsq ----
    int*      deg     = (int*)p;      p += align((size_t)N * 4);
    int*      ovf_cnt = (int*)p;      p += align(256);
    float*    gsum    = (float*)p;    p += align((size_t)D * 4);
    float*    gsumsq  = (float*)p;    p += align((size_t)D * 4);
    size_t zbytes = (size_t)(p - (char*)d_ws);
    // ---- rest ----
    ushort*   wbT      = (ushort*)p;   p += align((size_t)D * D * 2);
    int*      ell      = (int*)p;      p += align((size_t)N * K_ELL * 4);
    int2*     ovf      = (int2*)p;     p += align((size_t)EP * 8);
    ushort*   hb       = (ushort*)p;   p += align((size_t)N * D * 2);
    float*    partials = (float*)p;    p += align((size_t)NB_AGG * 256 * 4);

    hipMemsetAsync(d_ws, 0, zbytes, stream);
    prep<<<(EP + 255) / 256, 256, 0, stream>>>(prow, pcol, deg, ell, ovf, ovf_cnt,
                                               W, wbT, EP);
    gemm_mfma<<<(N + 63) / 64, 256, 0, stream>>>(x, wbT, hb, N);
    aggregate<<<NB_AGG, 512, 0, stream>>>((const unsigned*)hb, deg, ell, ovf, ovf_cnt,
                                          bias, out, partials, N);
    bn_reduce<<<64, 256, 0, stream>>>(partials, gsum, gsumsq, NB_AGG);
    bn_finalize<<<1600, 256, 0, stream>>>((float4*)out, gsum, gsumsq, gamma, beta,
                                          N * D / 4, 1.0f / (float)N);
}